// Round 1
// 492.049 us; speedup vs baseline: 1.0140x; 1.0140x over previous
//
#include <hip/hip_runtime.h>
#include <hip/hip_bf16.h>

// Problem constants
#define S_TOK 2048
#define DFF 11008
#define DMODEL 4096
#define TOPK 4403      // int(0.4 * 11008)
#define KPAD 4416      // TOPK padded up to multiple of 64
#define RSPLIT 16
#define RCHUNK 128     // 2048 / 16
#define TCH 11         // 11 * 1024 = 11264 >= 11008

typedef unsigned short u16;
typedef unsigned int u32;
typedef unsigned long long u64;
typedef __attribute__((ext_vector_type(8))) short short8;   // 8 x bf16 (4 VGPRs)
typedef __attribute__((ext_vector_type(4))) float floatx4;  // MFMA accumulator

// ---------------------------------------------------------------------------
// 1) partial scores: fp64 accumulation in a FIXED split-16 tree. Numeric path
//    (per-column, rows r0..r0+127 sequential) is BIT-IDENTICAL to the passing
//    version; only the load width changed (float4 = 4 columns per thread).
//    Grid (43,16) x 64 threads x 4 cols = 11008 exact.
// ---------------------------------------------------------------------------
__global__ __launch_bounds__(64) void score_partial_k(const float* __restrict__ x,
                                                      double* __restrict__ partials) {
  int c = (blockIdx.x * 64 + threadIdx.x) * 4;   // 43*64*4 == 11008 exact
  int r0 = blockIdx.y * RCHUNK;
  const float* p = x + (size_t)r0 * DFF + c;
  double a0 = 0.0, a1 = 0.0, a2 = 0.0, a3 = 0.0;
#pragma unroll 8
  for (int r = 0; r < RCHUNK; ++r) {
    float4 v = *(const float4*)(p + (size_t)r * DFF);
    a0 += (v.x > 0.f) ? (double)v.x : 0.0;
    a1 += (v.y > 0.f) ? (double)v.y : 0.0;
    a2 += (v.z > 0.f) ? (double)v.z : 0.0;
    a3 += (v.w > 0.f) ? (double)v.w : 0.0;
  }
  double* q = partials + (size_t)blockIdx.y * DFF + c;
  q[0] = a0; q[1] = a1; q[2] = a2; q[3] = a3;
}

// ---------------------------------------------------------------------------
// 1b) parallel reduce of the 16 partials (same sequential b=0..15 fp64 chain
//     as the old single-block phase A -> bit-identical scores -> identical
//     selection). Writes fp64 scores + 32-bit radix keys to global.
//     Moves 1.4 MB of fp64 streaming off the single-CU topk block.
// ---------------------------------------------------------------------------
__global__ __launch_bounds__(256) void reduce_scores_k(const double* __restrict__ partials,
                                                       double* __restrict__ scores,
                                                       u32* __restrict__ keys) {
  int j = blockIdx.x * 256 + threadIdx.x;   // 43*256 == 11008 exact
  double acc = 0.0;
#pragma unroll
  for (int b = 0; b < RSPLIT; ++b) acc += partials[(size_t)b * DFF + j];
  scores[j] = acc;
  keys[j] = (u32)(((u64)__double_as_longlong(acc)) >> 32);
}

// ---------------------------------------------------------------------------
// 2) top-K select, latency-optimized single block (no longer does the reduce).
//    - radix-select on 32-bit keys: 4 passes, per-wave histograms (HG=16)
//    - suffix-sum over 256 buckets via ONE-WAVE shuffle scan (2 barriers
//      instead of 16 per pass)
//    - exact tie-break of key32-equal columns on full fp64 key, lowest index
//      first (== lax.top_k order)
//    - wave-shuffle block scan for rank[]; rank[j] = #selected < j,
//      rank[DFF] = TOPK. Selection values provably identical to prior rounds.
// ---------------------------------------------------------------------------
#define HG 16  // histogram groups (one per wave)

__device__ __forceinline__ int block_incl_scan(int v, int tid, int* wsums) {
  int lane = tid & 63, wave = tid >> 6;
#pragma unroll
  for (int off = 1; off < 64; off <<= 1) {
    int n = __shfl_up(v, off, 64);
    if (lane >= off) v += n;
  }
  if (lane == 63) wsums[wave] = v;
  __syncthreads();
  if (wave == 0) {
    int w = (lane < 16) ? wsums[lane] : 0;
#pragma unroll
    for (int off = 1; off < 16; off <<= 1) {
      int n = __shfl_up(w, off, 64);
      if (lane >= off) w += n;
    }
    if (lane < 16) wsums[lane] = w;  // inclusive wave totals
  }
  __syncthreads();
  int base = (wave > 0) ? wsums[wave - 1] : 0;
  return base + v;
}

__global__ __launch_bounds__(1024) void topk32_k(const u32* __restrict__ keys,
                                                 const double* __restrict__ scores,
                                                 int* __restrict__ rank) {
  __shared__ u32 keysh[DFF];        // 44,032 B
  __shared__ int histw[HG * 256];   // 16,384 B
  __shared__ __align__(16) int sbuf[256];
  __shared__ int wsums[16];
  __shared__ u32 sh_prefix;
  __shared__ int sh_need;
  __shared__ int gcount;
  __shared__ int gidx[256];
  __shared__ u64 gkey[256];
  const int tid = threadIdx.x;
  const int wave = tid >> 6;

  // Phase A (slim): keys -> LDS (44 KB, coalesced)
#pragma unroll
  for (int s = 0; s < 11; ++s) {
    int j = tid + s * 1024;
    if (j < DFF) keysh[j] = keys[j];
  }
  if (tid == 0) gcount = 0;
  __syncthreads();

  // thread-local keys: 11 consecutive columns
  const int j0 = tid * TCH;
  u32 key[TCH];
#pragma unroll
  for (int i = 0; i < TCH; ++i) {
    int j = j0 + i;
    key[i] = (j < DFF) ? keysh[j] : 0u;
  }

  // 4-pass radix select (MSB-first 8-bit digits)
  u32 prefix = 0;
  int remaining = TOPK;
  for (int d = 3; d >= 0; --d) {
    for (int i = tid; i < HG * 256; i += 1024) histw[i] = 0;
    __syncthreads();
    const int hb = wave << 8;  // per-wave histogram: halves atomic serialization
#pragma unroll
    for (int i = 0; i < TCH; ++i) {
      if (j0 + i >= DFF) break;
      u32 k = key[i];
      bool match = (d == 3) || ((k >> ((d + 1) * 8)) == (prefix >> ((d + 1) * 8)));
      if (match) atomicAdd(&histw[hb + (int)((k >> (d * 8)) & 255u)], 1);
    }
    __syncthreads();
    if (tid < 256) {
      int ssum = 0;
#pragma unroll
      for (int w = 0; w < HG; ++w) ssum += histw[w * 256 + tid];
      sbuf[tid] = ssum;
    }
    __syncthreads();
    // suffix-sum over 256 buckets in ONE wave: lane l owns buckets 4l..4l+3.
    // sbuf[b] becomes sum_{b'>=b} hist[b'] — identical values to old loop.
    if (wave == 0) {
      const int lane = tid;
      int h0 = sbuf[4 * lane], h1 = sbuf[4 * lane + 1];
      int h2 = sbuf[4 * lane + 2], h3 = sbuf[4 * lane + 3];
      int t4 = h0 + h1 + h2 + h3;
      int suf = t4;
#pragma unroll
      for (int off = 1; off < 64; off <<= 1) {
        int v = __shfl_down(suf, off, 64);
        if (lane + off < 64) suf += v;
      }
      int above = suf - t4;  // sum over lanes > l  == sum_{b >= 4(l+1)}
      sbuf[4 * lane + 3] = above + h3;
      sbuf[4 * lane + 2] = above + h3 + h2;
      sbuf[4 * lane + 1] = above + h3 + h2 + h1;
      sbuf[4 * lane] = above + t4;
    }
    __syncthreads();
    if (tid < 256) {
      int c = sbuf[tid];
      int cn = (tid < 255) ? sbuf[tid + 1] : 0;
      if (c >= remaining && cn < remaining) {  // unique crossing bucket
        sh_prefix = prefix | ((u32)tid << (d * 8));
        sh_need = remaining - cn;
      }
    }
    __syncthreads();
    prefix = sh_prefix;
    remaining = sh_need;
    __syncthreads();
  }
  const u32 T = prefix;
  const int needEq = remaining;  // #to take among key32==T (>=1)

  // collect key32==T group (tiny; exact fp64 tie-break)
#pragma unroll
  for (int i = 0; i < TCH; ++i) {
    int j = j0 + i;
    if (j < DFF && key[i] == T) {
      int p = atomicAdd(&gcount, 1);
      if (p < 256) { gidx[p] = j; gkey[p] = (u64)__double_as_longlong(scores[j]); }
    }
  }
  __syncthreads();
  int gc = gcount; if (gc > 256) gc = 256;

  // selection mask + block scan -> rank[]
  bool sel[TCH];
  int cntSel = 0;
#pragma unroll
  for (int i = 0; i < TCH; ++i) {
    int j = j0 + i;
    bool s = false;
    if (j < DFF) {
      if (key[i] > T) s = true;
      else if (key[i] == T) {
        u64 myk = (u64)__double_as_longlong(scores[j]);
        int r = 0;
        for (int e = 0; e < gc; ++e) {
          u64 ke = gkey[e];
          if (ke > myk || (ke == myk && gidx[e] < j)) r++;
        }
        s = (r < needEq);
      }
    }
    sel[i] = s;
    cntSel += s ? 1 : 0;
  }
  int incl = block_incl_scan(cntSel, tid, wsums);
  int running = incl - cntSel;
#pragma unroll
  for (int i = 0; i < TCH; ++i) {
    int j = j0 + i;
    if (j < DFF) {
      rank[j] = running;
      if (sel[i]) running++;
    }
  }
  if (tid == 0) rank[DFF] = TOPK;
}

// ---------------------------------------------------------------------------
// 3) compaction gather (16 rows/block): coalesced float4 reads, LDS compaction
//    at rank[c]-rank[c0], dense pair-packed u32 stores. Pad-zero fused into
//    the blockIdx.x==0 blocks. GNR 8->16 halves rank traffic + block count.
// ---------------------------------------------------------------------------
__device__ __forceinline__ u16 f2bf_rne(float f) {
  unsigned u = __float_as_uint(f);
  unsigned r = (u + 0x7fffu + ((u >> 16) & 1u)) >> 16;
  return (u16)r;
}

#define GCW 1024
#define GNR 16

__global__ __launch_bounds__(256) void compact_gather_k(const float* __restrict__ src,
                                                        const int* __restrict__ rank,
                                                        u16* __restrict__ dst) {
  __shared__ u16 buf[GNR][GCW];   // 32 KiB
  __shared__ int sh_se[2];
  const int c0 = blockIdx.x * GCW;
  const int row0 = blockIdx.y * GNR;
  if (threadIdx.x == 0) {
    int cend = c0 + GCW; if (cend > DFF) cend = DFF;
    sh_se[0] = rank[c0];
    sh_se[1] = rank[cend];
  }
  // fused pad-zero: 13 pad cols x GNR rows = 208 stores by the x==0 blocks
  if (blockIdx.x == 0 && threadIdx.x < (KPAD - TOPK) * GNR) {
    int rr = threadIdx.x / (KPAD - TOPK);
    int k = threadIdx.x - rr * (KPAD - TOPK);
    dst[(size_t)(row0 + rr) * KPAD + TOPK + k] = 0;
  }
  __syncthreads();
  const int start = sh_se[0];
  const int total = sh_se[1] - start;

  const int c = c0 + threadIdx.x * 4;
  if (total > 0 && c < DFF) {
    int r0 = rank[c], r1 = rank[c + 1], r2 = rank[c + 2], r3 = rank[c + 3], r4 = rank[c + 4];
#pragma unroll
    for (int rr = 0; rr < GNR; ++rr) {
      float4 v = *(const float4*)(src + (size_t)(row0 + rr) * DFF + c);
      if (r1 > r0) buf[rr][r0 - start] = f2bf_rne(v.x);
      if (r2 > r1) buf[rr][r1 - start] = f2bf_rne(v.y);
      if (r3 > r2) buf[rr][r2 - start] = f2bf_rne(v.z);
      if (r4 > r3) buf[rr][r3 - start] = f2bf_rne(v.w);
    }
  }
  __syncthreads();
  if (total > 0) {
    const int odd = start & 1;
    const int np = (total - odd) >> 1;
#pragma unroll
    for (int rr = 0; rr < GNR; ++rr) {
      u16* d = dst + (size_t)(row0 + rr) * KPAD;
      if (odd && threadIdx.x == 0) d[start] = buf[rr][0];
      const u16* bb = &buf[rr][odd];
      u16* da = d + start + odd;  // 4B-aligned
      for (int t = threadIdx.x; t < np; t += 256) {
        u32 v = (u32)bb[2 * t] | ((u32)bb[2 * t + 1] << 16);
        *(u32*)(da + 2 * t) = v;
      }
      if (((total - odd) & 1) && threadIdx.x == 0) d[start + total - 1] = buf[rr][total - 1];
    }
  }
}

// ---------------------------------------------------------------------------
// 4) NT GEMM: C[M,N] f32 = A[M,K] bf16 · B[N,K] bf16^T  (unchanged)
// ---------------------------------------------------------------------------
#define BM 128
#define BN 128
#define BK 64

__device__ __forceinline__ void async_load16(const void* g, void* l) {
  __builtin_amdgcn_global_load_lds(
      (const __attribute__((address_space(1))) void*)g,
      (__attribute__((address_space(3))) void*)l, 16, 0, 0);
}

__global__ __launch_bounds__(256) void gemm_bt_k(const u16* __restrict__ A,
                                                 const u16* __restrict__ B,
                                                 float* __restrict__ C,
                                                 int M, int N, int Kt) {
  __shared__ __align__(16) u16 As[BM * BK];
  __shared__ __align__(16) u16 Bs[BN * BK];
  const int tid = threadIdx.x;
  const int lane = tid & 63;
  const int wave = tid >> 6;
  const int bm = blockIdx.y * BM;
  const int bn = blockIdx.x * BN;
  const int wrow = (wave >> 1) * 64;
  const int wcol = (wave & 1) * 64;

  floatx4 acc[4][4];
#pragma unroll
  for (int i = 0; i < 4; ++i)
#pragma unroll
    for (int j = 0; j < 4; ++j)
      acc[i][j] = (floatx4){0.f, 0.f, 0.f, 0.f};

  const int srow = wave * 8 + (lane >> 3);
  const int scol = (lane & 7) * 8;
  const u16* gA = A + (size_t)(bm + srow) * Kt + scol;
  const u16* gB = B + (size_t)(bn + srow) * Kt + scol;
  u16* lA = As + wave * 8 * BK;  // wave-uniform LDS base
  u16* lB = Bs + wave * 8 * BK;

  const u16* aptr = As + (wrow + (lane & 15)) * BK + (lane >> 4) * 8;
  const u16* bptr = Bs + (wcol + (lane & 15)) * BK + (lane >> 4) * 8;

  for (int k0 = 0; k0 < Kt; k0 += BK) {
#pragma unroll
    for (int i = 0; i < 4; ++i) {
      async_load16(gA + k0 + (size_t)i * 32 * Kt, lA + i * 32 * BK);
      async_load16(gB + k0 + (size_t)i * 32 * Kt, lB + i * 32 * BK);
    }
    __syncthreads();
#pragma unroll
    for (int ks = 0; ks < BK; ks += 32) {
      short8 af[4], bf[4];
#pragma unroll
      for (int i = 0; i < 4; ++i) af[i] = *(const short8*)(aptr + i * 16 * BK + ks);
#pragma unroll
      for (int j = 0; j < 4; ++j) bf[j] = *(const short8*)(bptr + j * 16 * BK + ks);
#pragma unroll
      for (int i = 0; i < 4; ++i)
#pragma unroll
        for (int j = 0; j < 4; ++j)
          acc[i][j] = __builtin_amdgcn_mfma_f32_16x16x32_bf16(af[i], bf[j], acc[i][j], 0, 0, 0);
    }
    __syncthreads();
  }

  // C/D layout (verified m89/m91): col = lane&15, row = (lane>>4)*4 + reg
#pragma unroll
  for (int i = 0; i < 4; ++i) {
#pragma unroll
    for (int j = 0; j < 4; ++j) {
      int row = bm + wrow + i * 16 + (lane >> 4) * 4;
      int col = bn + wcol + j * 16 + (lane & 15);
      float* p = C + (size_t)row * N + col;
#pragma unroll
      for (int r = 0; r < 4; ++r) p[(size_t)r * N] = acc[i][j][r];
    }
  }
}

// ---------------------------------------------------------------------------
// launch
// ---------------------------------------------------------------------------
extern "C" void kernel_launch(void* const* d_in, const int* in_sizes, int n_in,
                              void* d_out, int out_size, void* d_ws, size_t ws_size,
                              hipStream_t stream) {
  const float* x = (const float*)d_in[0];  // [2048, 11008]
  const float* W = (const float*)d_in[1];  // [4096, 11008]
  float* out = (float*)d_out;              // [2048, 4096]
  char* ws = (char*)d_ws;

  // workspace layout (~56 MB)
  double* partials = (double*)ws;                      // 16*11008*8 = 1,409,024 B
  double* scores = (double*)(ws + 1409024);            // 11008*8    =    88,064 B
  int* rank = (int*)(ws + 1409024 + 88064);            // (11008+1)*4 =  44,036 B
  u32* keys = (u32*)(ws + 1409024 + 88064 + 44040);    // 11008*4    =    44,032 B
  u16* Xg = (u16*)(ws + (size_t)2 * 1024 * 1024);      // 2048*4416*2 = 18,087,936 B
  u16* Wg = (u16*)(ws + (size_t)2 * 1024 * 1024 + (size_t)S_TOK * KPAD * 2);  // 4096*4416*2

  score_partial_k<<<dim3(43, RSPLIT), 64, 0, stream>>>(x, partials);
  reduce_scores_k<<<43, 256, 0, stream>>>(partials, scores, keys);
  topk32_k<<<1, 1024, 0, stream>>>(keys, scores, rank);
  compact_gather_k<<<dim3(11, S_TOK / GNR), 256, 0, stream>>>(x, rank, Xg);
  compact_gather_k<<<dim3(11, DMODEL / GNR), 256, 0, stream>>>(W, rank, Wg);
  gemm_bt_k<<<dim3(DMODEL / BN, S_TOK / BM), 256, 0, stream>>>(Xg, Wg, out, S_TOK, DMODEL, KPAD);
}

// Round 2
// 467.480 us; speedup vs baseline: 1.0673x; 1.0526x over previous
//
#include <hip/hip_runtime.h>
#include <hip/hip_bf16.h>

// Problem constants
#define S_TOK 2048
#define DFF 11008
#define DMODEL 4096
#define TOPK 4403      // int(0.4 * 11008)
#define KPAD 4480      // TOPK padded up to 70*64 (even # of 64-wide K-tiles)
#define NTILES 70      // KPAD/64
#define TSPLIT 36      // split-K boundary in tiles (36 + 34, both even)
#define RSPLIT 16
#define RCHUNK 128     // 2048 / 16
#define TCH 11         // 11 * 1024 = 11264 >= 11008

typedef unsigned short u16;
typedef unsigned int u32;
typedef unsigned long long u64;
typedef __attribute__((ext_vector_type(8))) short short8;   // 8 x bf16 (4 VGPRs)
typedef __attribute__((ext_vector_type(4))) float floatx4;  // MFMA accumulator

// ---------------------------------------------------------------------------
// 1) partial scores: fp64 accumulation in a FIXED split-16 tree (bit-identical
//    numeric path to the passing rounds; float4 load width only).
// ---------------------------------------------------------------------------
__global__ __launch_bounds__(64) void score_partial_k(const float* __restrict__ x,
                                                      double* __restrict__ partials) {
  int c = (blockIdx.x * 64 + threadIdx.x) * 4;   // 43*64*4 == 11008 exact
  int r0 = blockIdx.y * RCHUNK;
  const float* p = x + (size_t)r0 * DFF + c;
  double a0 = 0.0, a1 = 0.0, a2 = 0.0, a3 = 0.0;
#pragma unroll 8
  for (int r = 0; r < RCHUNK; ++r) {
    float4 v = *(const float4*)(p + (size_t)r * DFF);
    a0 += (v.x > 0.f) ? (double)v.x : 0.0;
    a1 += (v.y > 0.f) ? (double)v.y : 0.0;
    a2 += (v.z > 0.f) ? (double)v.z : 0.0;
    a3 += (v.w > 0.f) ? (double)v.w : 0.0;
  }
  double* q = partials + (size_t)blockIdx.y * DFF + c;
  q[0] = a0; q[1] = a1; q[2] = a2; q[3] = a3;
}

// ---------------------------------------------------------------------------
// 1b) parallel reduce of the 16 partials (same sequential b=0..15 fp64 chain
//     -> bit-identical scores -> identical selection).
// ---------------------------------------------------------------------------
__global__ __launch_bounds__(256) void reduce_scores_k(const double* __restrict__ partials,
                                                       double* __restrict__ scores,
                                                       u32* __restrict__ keys) {
  int j = blockIdx.x * 256 + threadIdx.x;   // 43*256 == 11008 exact
  double acc = 0.0;
#pragma unroll
  for (int b = 0; b < RSPLIT; ++b) acc += partials[(size_t)b * DFF + j];
  scores[j] = acc;
  keys[j] = (u32)(((u64)__double_as_longlong(acc)) >> 32);
}

// ---------------------------------------------------------------------------
// 2) top-K select, single block (selection provably identical to prior rounds)
// ---------------------------------------------------------------------------
#define HG 16  // histogram groups (one per wave)

__device__ __forceinline__ int block_incl_scan(int v, int tid, int* wsums) {
  int lane = tid & 63, wave = tid >> 6;
#pragma unroll
  for (int off = 1; off < 64; off <<= 1) {
    int n = __shfl_up(v, off, 64);
    if (lane >= off) v += n;
  }
  if (lane == 63) wsums[wave] = v;
  __syncthreads();
  if (wave == 0) {
    int w = (lane < 16) ? wsums[lane] : 0;
#pragma unroll
    for (int off = 1; off < 16; off <<= 1) {
      int n = __shfl_up(w, off, 64);
      if (lane >= off) w += n;
    }
    if (lane < 16) wsums[lane] = w;  // inclusive wave totals
  }
  __syncthreads();
  int base = (wave > 0) ? wsums[wave - 1] : 0;
  return base + v;
}

__global__ __launch_bounds__(1024) void topk32_k(const u32* __restrict__ keys,
                                                 const double* __restrict__ scores,
                                                 int* __restrict__ rank) {
  __shared__ u32 keysh[DFF];        // 44,032 B
  __shared__ int histw[HG * 256];   // 16,384 B
  __shared__ __align__(16) int sbuf[256];
  __shared__ int wsums[16];
  __shared__ u32 sh_prefix;
  __shared__ int sh_need;
  __shared__ int gcount;
  __shared__ int gidx[256];
  __shared__ u64 gkey[256];
  const int tid = threadIdx.x;
  const int wave = tid >> 6;

  // Phase A (slim): keys -> LDS (44 KB, coalesced)
#pragma unroll
  for (int s = 0; s < 11; ++s) {
    int j = tid + s * 1024;
    if (j < DFF) keysh[j] = keys[j];
  }
  if (tid == 0) gcount = 0;
  __syncthreads();

  const int j0 = tid * TCH;
  u32 key[TCH];
#pragma unroll
  for (int i = 0; i < TCH; ++i) {
    int j = j0 + i;
    key[i] = (j < DFF) ? keysh[j] : 0u;
  }

  // 4-pass radix select (MSB-first 8-bit digits)
  u32 prefix = 0;
  int remaining = TOPK;
  for (int d = 3; d >= 0; --d) {
    for (int i = tid; i < HG * 256; i += 1024) histw[i] = 0;
    __syncthreads();
    const int hb = wave << 8;
#pragma unroll
    for (int i = 0; i < TCH; ++i) {
      if (j0 + i >= DFF) break;
      u32 k = key[i];
      bool match = (d == 3) || ((k >> ((d + 1) * 8)) == (prefix >> ((d + 1) * 8)));
      if (match) atomicAdd(&histw[hb + (int)((k >> (d * 8)) & 255u)], 1);
    }
    __syncthreads();
    if (tid < 256) {
      int ssum = 0;
#pragma unroll
      for (int w = 0; w < HG; ++w) ssum += histw[w * 256 + tid];
      sbuf[tid] = ssum;
    }
    __syncthreads();
    // suffix-sum over 256 buckets in ONE wave: lane l owns buckets 4l..4l+3.
    if (wave == 0) {
      const int lane = tid;
      int h0 = sbuf[4 * lane], h1 = sbuf[4 * lane + 1];
      int h2 = sbuf[4 * lane + 2], h3 = sbuf[4 * lane + 3];
      int t4 = h0 + h1 + h2 + h3;
      int suf = t4;
#pragma unroll
      for (int off = 1; off < 64; off <<= 1) {
        int v = __shfl_down(suf, off, 64);
        if (lane + off < 64) suf += v;
      }
      int above = suf - t4;
      sbuf[4 * lane + 3] = above + h3;
      sbuf[4 * lane + 2] = above + h3 + h2;
      sbuf[4 * lane + 1] = above + h3 + h2 + h1;
      sbuf[4 * lane] = above + t4;
    }
    __syncthreads();
    if (tid < 256) {
      int c = sbuf[tid];
      int cn = (tid < 255) ? sbuf[tid + 1] : 0;
      if (c >= remaining && cn < remaining) {
        sh_prefix = prefix | ((u32)tid << (d * 8));
        sh_need = remaining - cn;
      }
    }
    __syncthreads();
    prefix = sh_prefix;
    remaining = sh_need;
    __syncthreads();
  }
  const u32 T = prefix;
  const int needEq = remaining;

  // collect key32==T group (tiny; exact fp64 tie-break)
#pragma unroll
  for (int i = 0; i < TCH; ++i) {
    int j = j0 + i;
    if (j < DFF && key[i] == T) {
      int p = atomicAdd(&gcount, 1);
      if (p < 256) { gidx[p] = j; gkey[p] = (u64)__double_as_longlong(scores[j]); }
    }
  }
  __syncthreads();
  int gc = gcount; if (gc > 256) gc = 256;

  bool sel[TCH];
  int cntSel = 0;
#pragma unroll
  for (int i = 0; i < TCH; ++i) {
    int j = j0 + i;
    bool s = false;
    if (j < DFF) {
      if (key[i] > T) s = true;
      else if (key[i] == T) {
        u64 myk = (u64)__double_as_longlong(scores[j]);
        int r = 0;
        for (int e = 0; e < gc; ++e) {
          u64 ke = gkey[e];
          if (ke > myk || (ke == myk && gidx[e] < j)) r++;
        }
        s = (r < needEq);
      }
    }
    sel[i] = s;
    cntSel += s ? 1 : 0;
  }
  int incl = block_incl_scan(cntSel, tid, wsums);
  int running = incl - cntSel;
#pragma unroll
  for (int i = 0; i < TCH; ++i) {
    int j = j0 + i;
    if (j < DFF) {
      rank[j] = running;
      if (sel[i]) running++;
    }
  }
  if (tid == 0) rank[DFF] = TOPK;
}

// ---------------------------------------------------------------------------
// 3) compaction gather (16 rows/block); pad-zero covers [TOPK, KPAD)
// ---------------------------------------------------------------------------
__device__ __forceinline__ u16 f2bf_rne(float f) {
  unsigned u = __float_as_uint(f);
  unsigned r = (u + 0x7fffu + ((u >> 16) & 1u)) >> 16;
  return (u16)r;
}

#define GCW 1024
#define GNR 16

__global__ __launch_bounds__(256) void compact_gather_k(const float* __restrict__ src,
                                                        const int* __restrict__ rank,
                                                        u16* __restrict__ dst) {
  __shared__ u16 buf[GNR][GCW];   // 32 KiB
  __shared__ int sh_se[2];
  const int c0 = blockIdx.x * GCW;
  const int row0 = blockIdx.y * GNR;
  if (threadIdx.x == 0) {
    int cend = c0 + GCW; if (cend > DFF) cend = DFF;
    sh_se[0] = rank[c0];
    sh_se[1] = rank[cend];
  }
  // fused pad-zero: (KPAD-TOPK)=77 pad cols x GNR rows by the x==0 blocks
  if (blockIdx.x == 0) {
    for (int idx = threadIdx.x; idx < (KPAD - TOPK) * GNR; idx += 256) {
      int rr = idx / (KPAD - TOPK);
      int k = idx - rr * (KPAD - TOPK);
      dst[(size_t)(row0 + rr) * KPAD + TOPK + k] = 0;
    }
  }
  __syncthreads();
  const int start = sh_se[0];
  const int total = sh_se[1] - start;

  const int c = c0 + threadIdx.x * 4;
  if (total > 0 && c < DFF) {
    int r0 = rank[c], r1 = rank[c + 1], r2 = rank[c + 2], r3 = rank[c + 3], r4 = rank[c + 4];
#pragma unroll
    for (int rr = 0; rr < GNR; ++rr) {
      float4 v = *(const float4*)(src + (size_t)(row0 + rr) * DFF + c);
      if (r1 > r0) buf[rr][r0 - start] = f2bf_rne(v.x);
      if (r2 > r1) buf[rr][r1 - start] = f2bf_rne(v.y);
      if (r3 > r2) buf[rr][r2 - start] = f2bf_rne(v.z);
      if (r4 > r3) buf[rr][r3 - start] = f2bf_rne(v.w);
    }
  }
  __syncthreads();
  if (total > 0) {
    const int odd = start & 1;
    const int np = (total - odd) >> 1;
#pragma unroll
    for (int rr = 0; rr < GNR; ++rr) {
      u16* d = dst + (size_t)(row0 + rr) * KPAD;
      if (odd && threadIdx.x == 0) d[start] = buf[rr][0];
      const u16* bb = &buf[rr][odd];
      u16* da = d + start + odd;
      for (int t = threadIdx.x; t < np; t += 256) {
        u32 v = (u32)bb[2 * t] | ((u32)bb[2 * t + 1] << 16);
        *(u32*)(da + 2 * t) = v;
      }
      if (((total - odd) & 1) && threadIdx.x == 0) d[start + total - 1] = buf[rr][total - 1];
    }
  }
}

// ---------------------------------------------------------------------------
// 4) NT GEMM, 256x256 tile, BK=64, 8 waves (2Mx4N), 8-phase counted-vmcnt
//    schedule (T2 swizzle + T3/T4 pipeline + T5 setprio).
//    C[M,N] f32 = A[M,K] bf16 . B[N,K] bf16^T over K-tiles [tile0, tile1).
//
//    LDS 128 KiB: buf0.A[0,32K) buf0.B[32K,64K) buf1.A[64K,96K) buf1.B[96K,128K)
//    Swizzle (both sides): tile_byte ^= ((row&7)<<4)  [G4-proven pattern]
//    Phase table per iteration (tiles t->buf0, t+1->buf1):
//      p0: ldA(buf0,q01)+ldB(buf0,c0-31->bfA); stage A(t+1)h0->buf1; MFMA(0,0)
//      p1: ldB(buf0,c32-63->bfB);              stage A(t+1)h1->buf1; MFMA(0,1)
//      p2: ldA(buf0,q23);                      stage B(t+2)h0->buf0; MFMA(1,0)
//      p3:                                     stage B(t+2)h1->buf0; MFMA(1,1); vmcnt(4)
//      p4-p7: same with buf1/tile t+1, staging A(t+2)->buf0, B(t+3)->buf1; vmcnt(4)@p7
//    WAR: B LDS regions are re-used from registers at p2/p3 (bfA/bfB persist),
//    so staging B at p2/p3 is safe; A regions free after p2/p5. vmcnt(4) at
//    p3/p7 drains exactly through the half-tiles read 1 phase later.
// ---------------------------------------------------------------------------
__device__ __forceinline__ void async_load16(const void* g, void* l) {
  __builtin_amdgcn_global_load_lds(
      (const __attribute__((address_space(1))) void*)g,
      (__attribute__((address_space(3))) void*)l, 16, 0, 0);
}

#define GBAR() do { asm volatile("" ::: "memory"); __builtin_amdgcn_s_barrier(); asm volatile("" ::: "memory"); } while (0)
#define VMCNT4() asm volatile("s_waitcnt vmcnt(4)" ::: "memory")

#define LOAD_A(D, QR) do {                                                  \
  const char* ab_ = (const char*)lds + (D) * 65536 + aRowByte + (QR) * 8192; \
  _Pragma("unroll") for (int i_ = 0; i_ < 4; ++i_) {                        \
    af[i_][0] = *(const short8*)(ab_ + i_ * 2048 + cs0);                    \
    af[i_][1] = *(const short8*)(ab_ + i_ * 2048 + cs1);                    \
  }                                                                         \
} while (0)

#define LOAD_B(D, QC, BF) do {                                              \
  const char* bb_ = (const char*)lds + (D) * 65536 + 32768 + bRowByte + (QC) * 4096; \
  _Pragma("unroll") for (int j_ = 0; j_ < 2; ++j_) {                        \
    BF[j_][0] = *(const short8*)(bb_ + j_ * 2048 + cs0);                    \
    BF[j_][1] = *(const short8*)(bb_ + j_ * 2048 + cs1);                    \
  }                                                                         \
} while (0)

#define MFMA_QUAD(QR, QC, BF) do {                                          \
  __builtin_amdgcn_s_setprio(1);                                            \
  _Pragma("unroll") for (int i_ = 0; i_ < 4; ++i_)                          \
    _Pragma("unroll") for (int j_ = 0; j_ < 2; ++j_)                        \
      _Pragma("unroll") for (int k_ = 0; k_ < 2; ++k_)                      \
        acc[(QR) * 4 + i_][(QC) * 2 + j_] = __builtin_amdgcn_mfma_f32_16x16x32_bf16( \
            af[i_][k_], BF[j_][k_], acc[(QR) * 4 + i_][(QC) * 2 + j_], 0, 0, 0); \
  __builtin_amdgcn_s_setprio(0);                                            \
} while (0)

// ldsbyte = wave-uniform half-tile base; HW appends lane*16.
#define STAGE_HALF(gp, grow0, ldsbyte, tt) do {                             \
  int ts_ = (tt); if (ts_ > lastTile) ts_ = lastTile;                       \
  const u16* s_ = (gp) + (size_t)((grow0) + sr0) * KPAD + ts_ * 64 + scc;   \
  async_load16(s_, (char*)lds + (ldsbyte) + wave * 1024);                   \
  async_load16(s_ + (size_t)64 * KPAD, (char*)lds + (ldsbyte) + 8192 + wave * 1024); \
} while (0)

__global__ __launch_bounds__(512, 2) void gemm8_k(const u16* __restrict__ A,
                                                  const u16* __restrict__ B,
                                                  float* __restrict__ Cbase,
                                                  int M, int N, int tsplit, int ntiles) {
  __shared__ __align__(16) u16 lds[65536];  // 128 KiB
  const int tid = threadIdx.x;
  const int lane = tid & 63;
  const int wave = tid >> 6;
  const int wr = wave >> 2, wc = wave & 3;

  // XCD-aware swizzle (gridDim.x is 128: %8==0, simple form bijective)
  const int nwg = gridDim.x;
  const int cpx = nwg >> 3;
  const int swz = (blockIdx.x & 7) * cpx + (blockIdx.x >> 3);
  const int nbn = N / 256;
  const int bm = (swz / nbn) * 256;
  const int bn = (swz % nbn) * 256;

  const int tile0 = blockIdx.y ? tsplit : 0;
  const int tile1 = blockIdx.y ? ntiles : tsplit;
  const int niter = (tile1 - tile0) >> 1;   // tile counts are even
  const int lastTile = tile1 - 1;
  float* Cout = Cbase + (size_t)blockIdx.y * M * N;

  // staging lane constants (inverse-swizzled global source)
  const int sr0 = wave * 8 + (lane >> 3);
  const int scc = ((lane & 7) ^ (lane >> 3)) * 8;
  // read-side swizzled column bytes: colpart ^ ((row&7)<<4), row&7 == lane&7
  const int cs0 = ((lane >> 4) * 16) ^ ((lane & 7) << 4);
  const int cs1 = cs0 ^ 64;
  const int aRowByte = (wr * 128 + (lane & 15)) * 128;
  const int bRowByte = (wc * 64 + (lane & 15)) * 128;

  floatx4 acc[8][4];
#pragma unroll
  for (int i = 0; i < 8; ++i)
#pragma unroll
    for (int j = 0; j < 4; ++j) acc[i][j] = (floatx4){0.f, 0.f, 0.f, 0.f};

  short8 af[4][2], bfA[2][2], bfB[2][2];

  // prologue: B(t0)->buf0.B, A(t0)->buf0.A, B(t0+1)->buf1.B  (12 loads)
  STAGE_HALF(B, bn + 0,   32768,  tile0);
  STAGE_HALF(B, bn + 128, 49152,  tile0);
  STAGE_HALF(A, bm + 0,   0,      tile0);
  STAGE_HALF(A, bm + 128, 16384,  tile0);
  STAGE_HALF(B, bn + 0,   98304,  tile0 + 1);
  STAGE_HALF(B, bn + 128, 114688, tile0 + 1);
  VMCNT4();   // t0 fully landed; B(t0+1) still in flight
  GBAR();

  for (int it = 0; it < niter; ++it) {
    const int t = tile0 + 2 * it;
    // p0
    LOAD_A(0, 0); LOAD_B(0, 0, bfA);
    STAGE_HALF(A, bm + 0, 65536, t + 1);
    GBAR(); MFMA_QUAD(0, 0, bfA); GBAR();
    // p1
    LOAD_B(0, 1, bfB);
    STAGE_HALF(A, bm + 128, 81920, t + 1);
    GBAR(); MFMA_QUAD(0, 1, bfB); GBAR();
    // p2
    LOAD_A(0, 1);
    STAGE_HALF(B, bn + 0, 32768, t + 2);
    GBAR(); MFMA_QUAD(1, 0, bfA); GBAR();
    // p3
    STAGE_HALF(B, bn + 128, 49152, t + 2);
    GBAR(); MFMA_QUAD(1, 1, bfB); VMCNT4(); GBAR();
    // p4
    LOAD_A(1, 0); LOAD_B(1, 0, bfA);
    STAGE_HALF(A, bm + 0, 0, t + 2);
    GBAR(); MFMA_QUAD(0, 0, bfA); GBAR();
    // p5
    LOAD_B(1, 1, bfB);
    STAGE_HALF(A, bm + 128, 16384, t + 2);
    GBAR(); MFMA_QUAD(0, 1, bfB); GBAR();
    // p6
    LOAD_A(1, 1);
    STAGE_HALF(B, bn + 0, 98304, t + 3);
    GBAR(); MFMA_QUAD(1, 0, bfA); GBAR();
    // p7
    STAGE_HALF(B, bn + 128, 114688, t + 3);
    GBAR(); MFMA_QUAD(1, 1, bfB); VMCNT4(); GBAR();
  }

  // C/D layout (verified m89/m91): col = lane&15, row = (lane>>4)*4 + reg
#pragma unroll
  for (int fi = 0; fi < 8; ++fi) {
#pragma unroll
    for (int fj = 0; fj < 4; ++fj) {
      int row = bm + wr * 128 + fi * 16 + (lane >> 4) * 4;
      int col = bn + wc * 64 + fj * 16 + (lane & 15);
      float* p = Cout + (size_t)row * N + col;
#pragma unroll
      for (int r = 0; r < 4; ++r) p[(size_t)r * N] = acc[fi][fj][r];
    }
  }
}

// split-K combine: out = c0 + c1
__global__ __launch_bounds__(256) void addc_k(const float* __restrict__ a,
                                              const float* __restrict__ b,
                                              float* __restrict__ o, int n4) {
  int i = blockIdx.x * 256 + threadIdx.x;
  int stride = gridDim.x * 256;
  for (; i < n4; i += stride) {
    float4 x = ((const float4*)a)[i];
    float4 y = ((const float4*)b)[i];
    x.x += y.x; x.y += y.y; x.z += y.z; x.w += y.w;
    ((float4*)o)[i] = x;
  }
}

// ---------------------------------------------------------------------------
// launch
// ---------------------------------------------------------------------------
extern "C" void kernel_launch(void* const* d_in, const int* in_sizes, int n_in,
                              void* d_out, int out_size, void* d_ws, size_t ws_size,
                              hipStream_t stream) {
  const float* x = (const float*)d_in[0];  // [2048, 11008]
  const float* W = (const float*)d_in[1];  // [4096, 11008]
  float* out = (float*)d_out;              // [2048, 4096]
  char* ws = (char*)d_ws;

  // workspace layout
  double* partials = (double*)ws;                        // 1,409,024 B
  double* scores = (double*)(ws + 1409024);              //    88,064 B
  int* rank = (int*)(ws + 1409024 + 88064);              //    44,036 B
  u32* keys = (u32*)(ws + 1409024 + 88064 + 44040);      //    44,032 B
  u16* Xg = (u16*)(ws + (size_t)2097152);                // 2048*4480*2 = 18,350,080
  u16* Wg = (u16*)(ws + (size_t)2097152 + (size_t)S_TOK * KPAD * 2);  // 36,700,160
  const size_t c0_off = 2097152 + (size_t)S_TOK * KPAD * 2 + (size_t)DMODEL * KPAD * 2; // 57,147,392
  float* c0 = (float*)(ws + c0_off);
  float* c1 = c0 + (size_t)S_TOK * DMODEL;
  const size_t ws_need = c0_off + (size_t)2 * S_TOK * DMODEL * 4;  // 124,256,256

  score_partial_k<<<dim3(43, RSPLIT), 64, 0, stream>>>(x, partials);
  reduce_scores_k<<<43, 256, 0, stream>>>(partials, scores, keys);
  topk32_k<<<1, 1024, 0, stream>>>(keys, scores, rank);
  compact_gather_k<<<dim3(11, S_TOK / GNR), 256, 0, stream>>>(x, rank, Xg);
  compact_gather_k<<<dim3(11, DMODEL / GNR), 256, 0, stream>>>(W, rank, Wg);

  if (ws_size >= ws_need) {
    // split-K=2: 256 blocks (1/CU), partials then combine
    gemm8_k<<<dim3((S_TOK / 256) * (DMODEL / 256), 2), 512, 0, stream>>>(
        Xg, Wg, c0, S_TOK, DMODEL, TSPLIT, NTILES);
    addc_k<<<2048, 256, 0, stream>>>(c0, c1, out, (S_TOK * DMODEL) / 4);
  } else {
    // fallback: single pass over all 70 tiles (128 blocks)
    gemm8_k<<<dim3((S_TOK / 256) * (DMODEL / 256), 1), 512, 0, stream>>>(
        Xg, Wg, out, S_TOK, DMODEL, NTILES, NTILES);
  }
}

// Round 3
// 460.846 us; speedup vs baseline: 1.0826x; 1.0144x over previous
//
#include <hip/hip_runtime.h>
#include <hip/hip_bf16.h>

// Problem constants
#define S_TOK 2048
#define DFF 11008
#define DMODEL 4096
#define TOPK 4403      // int(0.4 * 11008)
#define KPAD 4480      // TOPK padded up to 70*64 K-tiles
#define NTILES 70      // KPAD/64
#define RSPLIT 16
#define RCHUNK 128     // 2048 / 16
#define TCH 11         // 11 * 1024 = 11264 >= 11008

typedef unsigned short u16;
typedef unsigned int u32;
typedef unsigned long long u64;
typedef __attribute__((ext_vector_type(8))) short short8;   // 8 x bf16 (4 VGPRs)
typedef __attribute__((ext_vector_type(4))) float floatx4;  // MFMA accumulator

// ---------------------------------------------------------------------------
// 1) partial scores: fp64 accumulation in a FIXED split-16 tree (bit-identical
//    numeric path to the passing rounds).
// ---------------------------------------------------------------------------
__global__ __launch_bounds__(64) void score_partial_k(const float* __restrict__ x,
                                                      double* __restrict__ partials) {
  int c = (blockIdx.x * 64 + threadIdx.x) * 4;   // 43*64*4 == 11008 exact
  int r0 = blockIdx.y * RCHUNK;
  const float* p = x + (size_t)r0 * DFF + c;
  double a0 = 0.0, a1 = 0.0, a2 = 0.0, a3 = 0.0;
#pragma unroll 8
  for (int r = 0; r < RCHUNK; ++r) {
    float4 v = *(const float4*)(p + (size_t)r * DFF);
    a0 += (v.x > 0.f) ? (double)v.x : 0.0;
    a1 += (v.y > 0.f) ? (double)v.y : 0.0;
    a2 += (v.z > 0.f) ? (double)v.z : 0.0;
    a3 += (v.w > 0.f) ? (double)v.w : 0.0;
  }
  double* q = partials + (size_t)blockIdx.y * DFF + c;
  q[0] = a0; q[1] = a1; q[2] = a2; q[3] = a3;
}

// ---------------------------------------------------------------------------
// 1b) parallel reduce of the 16 partials (same sequential b=0..15 fp64 chain
//     -> bit-identical scores -> identical selection).
// ---------------------------------------------------------------------------
__global__ __launch_bounds__(256) void reduce_scores_k(const double* __restrict__ partials,
                                                       double* __restrict__ scores,
                                                       u32* __restrict__ keys) {
  int j = blockIdx.x * 256 + threadIdx.x;   // 43*256 == 11008 exact
  double acc = 0.0;
#pragma unroll
  for (int b = 0; b < RSPLIT; ++b) acc += partials[(size_t)b * DFF + j];
  scores[j] = acc;
  keys[j] = (u32)(((u64)__double_as_longlong(acc)) >> 32);
}

// ---------------------------------------------------------------------------
// 2) top-K select, single block (selection provably identical to prior rounds)
// ---------------------------------------------------------------------------
#define HG 16  // histogram groups (one per wave)

__device__ __forceinline__ int block_incl_scan(int v, int tid, int* wsums) {
  int lane = tid & 63, wave = tid >> 6;
#pragma unroll
  for (int off = 1; off < 64; off <<= 1) {
    int n = __shfl_up(v, off, 64);
    if (lane >= off) v += n;
  }
  if (lane == 63) wsums[wave] = v;
  __syncthreads();
  if (wave == 0) {
    int w = (lane < 16) ? wsums[lane] : 0;
#pragma unroll
    for (int off = 1; off < 16; off <<= 1) {
      int n = __shfl_up(w, off, 64);
      if (lane >= off) w += n;
    }
    if (lane < 16) wsums[lane] = w;  // inclusive wave totals
  }
  __syncthreads();
  int base = (wave > 0) ? wsums[wave - 1] : 0;
  return base + v;
}

__global__ __launch_bounds__(1024) void topk32_k(const u32* __restrict__ keys,
                                                 const double* __restrict__ scores,
                                                 int* __restrict__ rank) {
  __shared__ u32 keysh[DFF];        // 44,032 B
  __shared__ int histw[HG * 256];   // 16,384 B
  __shared__ __align__(16) int sbuf[256];
  __shared__ int wsums[16];
  __shared__ u32 sh_prefix;
  __shared__ int sh_need;
  __shared__ int gcount;
  __shared__ int gidx[256];
  __shared__ u64 gkey[256];
  const int tid = threadIdx.x;
  const int wave = tid >> 6;

  // Phase A (slim): keys -> LDS (44 KB, coalesced)
#pragma unroll
  for (int s = 0; s < 11; ++s) {
    int j = tid + s * 1024;
    if (j < DFF) keysh[j] = keys[j];
  }
  if (tid == 0) gcount = 0;
  __syncthreads();

  const int j0 = tid * TCH;
  u32 key[TCH];
#pragma unroll
  for (int i = 0; i < TCH; ++i) {
    int j = j0 + i;
    key[i] = (j < DFF) ? keysh[j] : 0u;
  }

  // 4-pass radix select (MSB-first 8-bit digits)
  u32 prefix = 0;
  int remaining = TOPK;
  for (int d = 3; d >= 0; --d) {
    for (int i = tid; i < HG * 256; i += 1024) histw[i] = 0;
    __syncthreads();
    const int hb = wave << 8;
#pragma unroll
    for (int i = 0; i < TCH; ++i) {
      if (j0 + i >= DFF) break;
      u32 k = key[i];
      bool match = (d == 3) || ((k >> ((d + 1) * 8)) == (prefix >> ((d + 1) * 8)));
      if (match) atomicAdd(&histw[hb + (int)((k >> (d * 8)) & 255u)], 1);
    }
    __syncthreads();
    if (tid < 256) {
      int ssum = 0;
#pragma unroll
      for (int w = 0; w < HG; ++w) ssum += histw[w * 256 + tid];
      sbuf[tid] = ssum;
    }
    __syncthreads();
    // suffix-sum over 256 buckets in ONE wave: lane l owns buckets 4l..4l+3.
    if (wave == 0) {
      const int lane = tid;
      int h0 = sbuf[4 * lane], h1 = sbuf[4 * lane + 1];
      int h2 = sbuf[4 * lane + 2], h3 = sbuf[4 * lane + 3];
      int t4 = h0 + h1 + h2 + h3;
      int suf = t4;
#pragma unroll
      for (int off = 1; off < 64; off <<= 1) {
        int v = __shfl_down(suf, off, 64);
        if (lane + off < 64) suf += v;
      }
      int above = suf - t4;
      sbuf[4 * lane + 3] = above + h3;
      sbuf[4 * lane + 2] = above + h3 + h2;
      sbuf[4 * lane + 1] = above + h3 + h2 + h1;
      sbuf[4 * lane] = above + t4;
    }
    __syncthreads();
    if (tid < 256) {
      int c = sbuf[tid];
      int cn = (tid < 255) ? sbuf[tid + 1] : 0;
      if (c >= remaining && cn < remaining) {
        sh_prefix = prefix | ((u32)tid << (d * 8));
        sh_need = remaining - cn;
      }
    }
    __syncthreads();
    prefix = sh_prefix;
    remaining = sh_need;
    __syncthreads();
  }
  const u32 T = prefix;
  const int needEq = remaining;

  // collect key32==T group (tiny; exact fp64 tie-break)
#pragma unroll
  for (int i = 0; i < TCH; ++i) {
    int j = j0 + i;
    if (j < DFF && key[i] == T) {
      int p = atomicAdd(&gcount, 1);
      if (p < 256) { gidx[p] = j; gkey[p] = (u64)__double_as_longlong(scores[j]); }
    }
  }
  __syncthreads();
  int gc = gcount; if (gc > 256) gc = 256;

  bool sel[TCH];
  int cntSel = 0;
#pragma unroll
  for (int i = 0; i < TCH; ++i) {
    int j = j0 + i;
    bool s = false;
    if (j < DFF) {
      if (key[i] > T) s = true;
      else if (key[i] == T) {
        u64 myk = (u64)__double_as_longlong(scores[j]);
        int r = 0;
        for (int e = 0; e < gc; ++e) {
          u64 ke = gkey[e];
          if (ke > myk || (ke == myk && gidx[e] < j)) r++;
        }
        s = (r < needEq);
      }
    }
    sel[i] = s;
    cntSel += s ? 1 : 0;
  }
  int incl = block_incl_scan(cntSel, tid, wsums);
  int running = incl - cntSel;
#pragma unroll
  for (int i = 0; i < TCH; ++i) {
    int j = j0 + i;
    if (j < DFF) {
      rank[j] = running;
      if (sel[i]) running++;
    }
  }
  if (tid == 0) rank[DFF] = TOPK;
}

// ---------------------------------------------------------------------------
// 3) merged compaction gather: one dispatch covers X (y<128) and W (y>=128).
//    16 rows/block; pad-zero covers [TOPK, KPAD).
// ---------------------------------------------------------------------------
__device__ __forceinline__ u16 f2bf_rne(float f) {
  unsigned u = __float_as_uint(f);
  unsigned r = (u + 0x7fffu + ((u >> 16) & 1u)) >> 16;
  return (u16)r;
}

#define GCW 1024
#define GNR 16
#define XBLKS (S_TOK / GNR)   // 128

__global__ __launch_bounds__(256) void compact_gather2_k(const float* __restrict__ x,
                                                         const float* __restrict__ W,
                                                         const int* __restrict__ rank,
                                                         u16* __restrict__ Xg,
                                                         u16* __restrict__ Wg) {
  __shared__ u16 buf[GNR][GCW];   // 32 KiB
  __shared__ int sh_se[2];
  const int by = blockIdx.y;
  const float* src;
  u16* dst;
  int row0;
  if (by < XBLKS) { src = x; dst = Xg; row0 = by * GNR; }
  else            { src = W; dst = Wg; row0 = (by - XBLKS) * GNR; }
  const int c0 = blockIdx.x * GCW;
  if (threadIdx.x == 0) {
    int cend = c0 + GCW; if (cend > DFF) cend = DFF;
    sh_se[0] = rank[c0];
    sh_se[1] = rank[cend];
  }
  // fused pad-zero: (KPAD-TOPK)=77 pad cols x GNR rows by the x==0 blocks
  if (blockIdx.x == 0) {
    for (int idx = threadIdx.x; idx < (KPAD - TOPK) * GNR; idx += 256) {
      int rr = idx / (KPAD - TOPK);
      int k = idx - rr * (KPAD - TOPK);
      dst[(size_t)(row0 + rr) * KPAD + TOPK + k] = 0;
    }
  }
  __syncthreads();
  const int start = sh_se[0];
  const int total = sh_se[1] - start;

  const int c = c0 + threadIdx.x * 4;
  if (total > 0 && c < DFF) {
    int r0 = rank[c], r1 = rank[c + 1], r2 = rank[c + 2], r3 = rank[c + 3], r4 = rank[c + 4];
#pragma unroll
    for (int rr = 0; rr < GNR; ++rr) {
      float4 v = *(const float4*)(src + (size_t)(row0 + rr) * DFF + c);
      if (r1 > r0) buf[rr][r0 - start] = f2bf_rne(v.x);
      if (r2 > r1) buf[rr][r1 - start] = f2bf_rne(v.y);
      if (r3 > r2) buf[rr][r2 - start] = f2bf_rne(v.z);
      if (r4 > r3) buf[rr][r3 - start] = f2bf_rne(v.w);
    }
  }
  __syncthreads();
  if (total > 0) {
    const int odd = start & 1;
    const int np = (total - odd) >> 1;
#pragma unroll
    for (int rr = 0; rr < GNR; ++rr) {
      u16* d = dst + (size_t)(row0 + rr) * KPAD;
      if (odd && threadIdx.x == 0) d[start] = buf[rr][0];
      const u16* bb = &buf[rr][odd];
      u16* da = d + start + odd;
      for (int t = threadIdx.x; t < np; t += 256) {
        u32 v = (u32)bb[2 * t] | ((u32)bb[2 * t + 1] << 16);
        *(u32*)(da + 2 * t) = v;
      }
      if (((total - odd) & 1) && threadIdx.x == 0) d[start + total - 1] = buf[rr][total - 1];
    }
  }
}

// ---------------------------------------------------------------------------
// 4) NT GEMM, 256x128 tile, BK=64, 8 waves (4M x 2N), single pass over all 70
//    K-tiles (no split-K, no combine). 4-phase counted-vmcnt schedule per tile
//    (T2 swizzle + T3/T4 pipeline + T5 setprio). 256 blocks = 1/CU.
//
//    LDS 96 KiB: bufD at D*49152: A rows 0..255 [0,32768), B rows 0..127
//    [32768,49152). Swizzle both sides: byte ^= ((row&7)<<4).
//    Per-tile phase table (tile t in bufD, D=t&1):
//      p0: ldA(h0)->afL, ldB(h0)->bfL; stage A(t+1)h0->bufD^1; BAR; Q00; BAR
//      p1: ldB(h1)->bfH;               stage A(t+1)h1->bufD^1; BAR; Q01; BAR
//      p2: ldA(h1)->afH;               stage B(t+2)op0->bufD;  BAR; Q10; BAR
//      p3:                             stage B(t+2)op1->bufD;       Q11; vmcnt(2); BAR
//    Ledger: iter start = 2 outstanding (B(t+1)); +2+2+1+1 = 8; vmcnt(2)
//    drains B(t+1)+A(t+1) (bufD^1 complete for next iter), keeps B(t+2) in
//    flight. WAR on bufD.B at p2/p3 is safe: all B reads landed in regs
//    (bfL/bfH) before p1's trailing barrier.
// ---------------------------------------------------------------------------
__device__ __forceinline__ void async_load16(const void* g, void* l) {
  __builtin_amdgcn_global_load_lds(
      (const __attribute__((address_space(1))) void*)g,
      (__attribute__((address_space(3))) void*)l, 16, 0, 0);
}

#define GBAR() do { asm volatile("" ::: "memory"); __builtin_amdgcn_s_barrier(); asm volatile("" ::: "memory"); } while (0)
#define VMCNT2() asm volatile("s_waitcnt vmcnt(2)" ::: "memory")

#define LD_A(D, HF, AF) do {                                                \
  const char* ab_ = (const char*)lds + (D) * 49152 + aBase + (HF) * 4096;   \
  _Pragma("unroll") for (int i_ = 0; i_ < 2; ++i_) {                        \
    AF[i_][0] = *(const short8*)(ab_ + i_ * 2048 + cs0);                    \
    AF[i_][1] = *(const short8*)(ab_ + i_ * 2048 + cs1);                    \
  }                                                                         \
} while (0)

#define LD_B(D, HF, BF) do {                                                \
  const char* bb_ = (const char*)lds + (D) * 49152 + bBase + (HF) * 4096;   \
  _Pragma("unroll") for (int j_ = 0; j_ < 2; ++j_) {                        \
    BF[j_][0] = *(const short8*)(bb_ + j_ * 2048 + cs0);                    \
    BF[j_][1] = *(const short8*)(bb_ + j_ * 2048 + cs1);                    \
  }                                                                         \
} while (0)

#define MQ(HR, HC, AF, BF) do {                                             \
  __builtin_amdgcn_s_setprio(1);                                            \
  _Pragma("unroll") for (int i_ = 0; i_ < 2; ++i_)                          \
    _Pragma("unroll") for (int j_ = 0; j_ < 2; ++j_)                        \
      _Pragma("unroll") for (int k_ = 0; k_ < 2; ++k_)                      \
        acc[(HR) * 2 + i_][(HC) * 2 + j_] = __builtin_amdgcn_mfma_f32_16x16x32_bf16( \
            AF[i_][k_], BF[j_][k_], acc[(HR) * 2 + i_][(HC) * 2 + j_], 0, 0, 0); \
  __builtin_amdgcn_s_setprio(0);                                            \
} while (0)

// stage 128 A-rows (2 loads) of tile tt, half HF, into bufD
#define STAGE_A2(tt, D, HF) do {                                            \
  int ts_ = (tt); if (ts_ > NTILES - 1) ts_ = NTILES - 1;                   \
  const u16* s_ = A + (size_t)(bm + (HF) * 128 + sr0) * KPAD + ts_ * 64 + scc; \
  char* l_ = (char*)lds + (D) * 49152 + (HF) * 16384 + wave * 1024;         \
  async_load16(s_, l_);                                                     \
  async_load16(s_ + (size_t)64 * KPAD, l_ + 8192);                          \
} while (0)

// stage 64 B-rows (1 load) of tile tt, op HF (rows HF*64..), into bufD
#define STAGE_B1(tt, D, HF) do {                                            \
  int ts_ = (tt); if (ts_ > NTILES - 1) ts_ = NTILES - 1;                   \
  const u16* s_ = B + (size_t)(bn + (HF) * 64 + sr0) * KPAD + ts_ * 64 + scc; \
  char* l_ = (char*)lds + (D) * 49152 + 32768 + (HF) * 8192 + wave * 1024;  \
  async_load16(s_, l_);                                                     \
} while (0)

#define ITER(T, D) do {                                                     \
  LD_A(D, 0, afL); LD_B(D, 0, bfL);                                         \
  STAGE_A2((T) + 1, (D) ^ 1, 0);                                            \
  GBAR(); MQ(0, 0, afL, bfL); GBAR();                                       \
  LD_B(D, 1, bfH);                                                          \
  STAGE_A2((T) + 1, (D) ^ 1, 1);                                            \
  GBAR(); MQ(0, 1, afL, bfH); GBAR();                                       \
  LD_A(D, 1, afH);                                                          \
  STAGE_B1((T) + 2, (D), 0);                                                \
  GBAR(); MQ(1, 0, afH, bfL); GBAR();                                       \
  STAGE_B1((T) + 2, (D), 1);                                                \
  MQ(1, 1, afH, bfH); VMCNT2(); GBAR();                                     \
} while (0)

__global__ __launch_bounds__(512, 2) void gemm8_k(const u16* __restrict__ A,
                                                  const u16* __restrict__ B,
                                                  float* __restrict__ C) {
  __shared__ __align__(16) u16 lds[49152];  // 96 KiB
  const int tid = threadIdx.x;
  const int lane = tid & 63;
  const int wave = tid >> 6;
  const int wr = wave >> 1, wc = wave & 1;   // 4M x 2N waves, 64x64 each

  // XCD-aware swizzle: 256 blocks, 32/XCD -> each XCD owns one full bm row
  const int swz = (blockIdx.x & 7) * 32 + (blockIdx.x >> 3);
  const int bm = (swz >> 5) * 256;           // 8 M-tiles
  const int bn = (swz & 31) * 128;           // 32 N-tiles

  // staging lane constants (inverse-swizzled global source)
  const int sr0 = wave * 8 + (lane >> 3);
  const int scc = ((lane & 7) ^ (lane >> 3)) * 8;
  // read-side swizzled column bytes: colpart ^ ((row&7)<<4), row&7 == lane&7
  const int cs0 = ((lane >> 4) * 16) ^ ((lane & 7) << 4);
  const int cs1 = cs0 ^ 64;
  const int aBase = (wr * 64 + (lane & 15)) * 128;
  const int bBase = 32768 + (wc * 64 + (lane & 15)) * 128;

  floatx4 acc[4][4];
#pragma unroll
  for (int i = 0; i < 4; ++i)
#pragma unroll
    for (int j = 0; j < 4; ++j) acc[i][j] = (floatx4){0.f, 0.f, 0.f, 0.f};

  short8 afL[2][2], afH[2][2], bfL[2][2], bfH[2][2];

  // prologue: A(0)->buf0 [4 loads], B(0)->buf0 [2], B(1)->buf1.B [2]
  STAGE_A2(0, 0, 0);
  STAGE_A2(0, 0, 1);
  STAGE_B1(0, 0, 0);
  STAGE_B1(0, 0, 1);
  STAGE_B1(1, 1, 0);
  STAGE_B1(1, 1, 1);
  VMCNT2();   // tile 0 fully landed; B(1) still in flight
  GBAR();

  for (int t2 = 0; t2 < NTILES; t2 += 2) {
    ITER(t2, 0);
    ITER(t2 + 1, 1);
  }

  // C/D layout (verified m89/m91): col = lane&15, row = (lane>>4)*4 + reg
#pragma unroll
  for (int fi = 0; fi < 4; ++fi) {
#pragma unroll
    for (int fj = 0; fj < 4; ++fj) {
      int row = bm + wr * 64 + fi * 16 + (lane >> 4) * 4;
      int col = bn + wc * 64 + fj * 16 + (lane & 15);
      float* p = C + (size_t)row * DMODEL + col;
#pragma unroll
      for (int r = 0; r < 4; ++r) p[(size_t)r * DMODEL] = acc[fi][fj][r];
    }
  }
}

// ---------------------------------------------------------------------------
// launch
// ---------------------------------------------------------------------------
extern "C" void kernel_launch(void* const* d_in, const int* in_sizes, int n_in,
                              void* d_out, int out_size, void* d_ws, size_t ws_size,
                              hipStream_t stream) {
  const float* x = (const float*)d_in[0];  // [2048, 11008]
  const float* W = (const float*)d_in[1];  // [4096, 11008]
  float* out = (float*)d_out;              // [2048, 4096]
  char* ws = (char*)d_ws;

  // workspace layout (~57 MB)
  double* partials = (double*)ws;                        // 1,409,024 B
  double* scores = (double*)(ws + 1409024);              //    88,064 B
  int* rank = (int*)(ws + 1409024 + 88064);              //    44,036 B
  u32* keys = (u32*)(ws + 1409024 + 88064 + 44040);      //    44,032 B
  u16* Xg = (u16*)(ws + (size_t)2097152);                // 2048*4480*2 = 18,350,080
  u16* Wg = (u16*)(ws + (size_t)2097152 + (size_t)S_TOK * KPAD * 2);  // 4096*4480*2

  score_partial_k<<<dim3(43, RSPLIT), 64, 0, stream>>>(x, partials);
  reduce_scores_k<<<43, 256, 0, stream>>>(partials, scores, keys);
  topk32_k<<<1, 1024, 0, stream>>>(keys, scores, rank);
  compact_gather2_k<<<dim3(11, XBLKS + DMODEL / GNR), 256, 0, stream>>>(x, W, rank, Xg, Wg);
  gemm8_k<<<dim3((S_TOK / 256) * (DMODEL / 128)), 512, 0, stream>>>(Xg, Wg, out);
}

// Round 4
// 449.104 us; speedup vs baseline: 1.1109x; 1.0261x over previous
//
#include <hip/hip_runtime.h>
#include <hip/hip_bf16.h>

// Problem constants
#define S_TOK 2048
#define DFF 11008
#define DMODEL 4096
#define TOPK 4403      // int(0.4 * 11008)
#define KPAD 4480      // TOPK padded up to 70*64 K-tiles
#define NTILES 70      // KPAD/64
#define RSPLIT 16
#define RCHUNK 128     // 2048 / 16
#define TCH 11         // 11 * 1024 = 11264 >= 11008

typedef unsigned short u16;
typedef unsigned int u32;
typedef unsigned long long u64;
typedef __attribute__((ext_vector_type(8))) short short8;   // 8 x bf16 (4 VGPRs)
typedef __attribute__((ext_vector_type(4))) float floatx4;  // MFMA accumulator

// ---------------------------------------------------------------------------
// 1) partial scores: fp64 accumulation in a FIXED split-16 tree (bit-identical
//    numeric path to the passing rounds). unroll 16: 16 independent float4
//    loads in flight per wave (grid is only ~2.7 waves/CU -> need wave ILP).
// ---------------------------------------------------------------------------
__global__ __launch_bounds__(64) void score_partial_k(const float* __restrict__ x,
                                                      double* __restrict__ partials) {
  int c = (blockIdx.x * 64 + threadIdx.x) * 4;   // 43*64*4 == 11008 exact
  int r0 = blockIdx.y * RCHUNK;
  const float* p = x + (size_t)r0 * DFF + c;
  double a0 = 0.0, a1 = 0.0, a2 = 0.0, a3 = 0.0;
#pragma unroll 16
  for (int r = 0; r < RCHUNK; ++r) {
    float4 v = *(const float4*)(p + (size_t)r * DFF);
    a0 += (v.x > 0.f) ? (double)v.x : 0.0;
    a1 += (v.y > 0.f) ? (double)v.y : 0.0;
    a2 += (v.z > 0.f) ? (double)v.z : 0.0;
    a3 += (v.w > 0.f) ? (double)v.w : 0.0;
  }
  double* q = partials + (size_t)blockIdx.y * DFF + c;
  q[0] = a0; q[1] = a1; q[2] = a2; q[3] = a3;
}

// ---------------------------------------------------------------------------
// 1b) parallel reduce of the 16 partials (same sequential b=0..15 fp64 chain
//     -> bit-identical scores -> identical selection).
// ---------------------------------------------------------------------------
__global__ __launch_bounds__(256) void reduce_scores_k(const double* __restrict__ partials,
                                                       double* __restrict__ scores,
                                                       u32* __restrict__ keys) {
  int j = blockIdx.x * 256 + threadIdx.x;   // 43*256 == 11008 exact
  double acc = 0.0;
#pragma unroll
  for (int b = 0; b < RSPLIT; ++b) acc += partials[(size_t)b * DFF + j];
  scores[j] = acc;
  keys[j] = (u32)(((u64)__double_as_longlong(acc)) >> 32);
}

// ---------------------------------------------------------------------------
// 2) top-K select, single block (selection provably identical to prior rounds)
// ---------------------------------------------------------------------------
#define HG 16  // histogram groups (one per wave)

__device__ __forceinline__ int block_incl_scan(int v, int tid, int* wsums) {
  int lane = tid & 63, wave = tid >> 6;
#pragma unroll
  for (int off = 1; off < 64; off <<= 1) {
    int n = __shfl_up(v, off, 64);
    if (lane >= off) v += n;
  }
  if (lane == 63) wsums[wave] = v;
  __syncthreads();
  if (wave == 0) {
    int w = (lane < 16) ? wsums[lane] : 0;
#pragma unroll
    for (int off = 1; off < 16; off <<= 1) {
      int n = __shfl_up(w, off, 64);
      if (lane >= off) w += n;
    }
    if (lane < 16) wsums[lane] = w;  // inclusive wave totals
  }
  __syncthreads();
  int base = (wave > 0) ? wsums[wave - 1] : 0;
  return base + v;
}

__global__ __launch_bounds__(1024) void topk32_k(const u32* __restrict__ keys,
                                                 const double* __restrict__ scores,
                                                 int* __restrict__ rank) {
  __shared__ u32 keysh[DFF];        // 44,032 B
  __shared__ int histw[HG * 256];   // 16,384 B
  __shared__ __align__(16) int sbuf[256];
  __shared__ int wsums[16];
  __shared__ u32 sh_prefix;
  __shared__ int sh_need;
  __shared__ int gcount;
  __shared__ int gidx[256];
  __shared__ u64 gkey[256];
  const int tid = threadIdx.x;
  const int wave = tid >> 6;

  // Phase A (slim): keys -> LDS (44 KB, coalesced)
#pragma unroll
  for (int s = 0; s < 11; ++s) {
    int j = tid + s * 1024;
    if (j < DFF) keysh[j] = keys[j];
  }
  if (tid == 0) gcount = 0;
  __syncthreads();

  const int j0 = tid * TCH;
  u32 key[TCH];
#pragma unroll
  for (int i = 0; i < TCH; ++i) {
    int j = j0 + i;
    key[i] = (j < DFF) ? keysh[j] : 0u;
  }

  // 4-pass radix select (MSB-first 8-bit digits)
  u32 prefix = 0;
  int remaining = TOPK;
  for (int d = 3; d >= 0; --d) {
    for (int i = tid; i < HG * 256; i += 1024) histw[i] = 0;
    __syncthreads();
    const int hb = wave << 8;
#pragma unroll
    for (int i = 0; i < TCH; ++i) {
      if (j0 + i >= DFF) break;
      u32 k = key[i];
      bool match = (d == 3) || ((k >> ((d + 1) * 8)) == (prefix >> ((d + 1) * 8)));
      if (match) atomicAdd(&histw[hb + (int)((k >> (d * 8)) & 255u)], 1);
    }
    __syncthreads();
    if (tid < 256) {
      int ssum = 0;
#pragma unroll
      for (int w = 0; w < HG; ++w) ssum += histw[w * 256 + tid];
      sbuf[tid] = ssum;
    }
    __syncthreads();
    // suffix-sum over 256 buckets in ONE wave: lane l owns buckets 4l..4l+3.
    if (wave == 0) {
      const int lane = tid;
      int h0 = sbuf[4 * lane], h1 = sbuf[4 * lane + 1];
      int h2 = sbuf[4 * lane + 2], h3 = sbuf[4 * lane + 3];
      int t4 = h0 + h1 + h2 + h3;
      int suf = t4;
#pragma unroll
      for (int off = 1; off < 64; off <<= 1) {
        int v = __shfl_down(suf, off, 64);
        if (lane + off < 64) suf += v;
      }
      int above = suf - t4;
      sbuf[4 * lane + 3] = above + h3;
      sbuf[4 * lane + 2] = above + h3 + h2;
      sbuf[4 * lane + 1] = above + h3 + h2 + h1;
      sbuf[4 * lane] = above + t4;
    }
    __syncthreads();
    if (tid < 256) {
      int c = sbuf[tid];
      int cn = (tid < 255) ? sbuf[tid + 1] : 0;
      if (c >= remaining && cn < remaining) {
        sh_prefix = prefix | ((u32)tid << (d * 8));
        sh_need = remaining - cn;
      }
    }
    __syncthreads();
    prefix = sh_prefix;
    remaining = sh_need;
    __syncthreads();
  }
  const u32 T = prefix;
  const int needEq = remaining;

  // collect key32==T group (tiny; exact fp64 tie-break)
#pragma unroll
  for (int i = 0; i < TCH; ++i) {
    int j = j0 + i;
    if (j < DFF && key[i] == T) {
      int p = atomicAdd(&gcount, 1);
      if (p < 256) { gidx[p] = j; gkey[p] = (u64)__double_as_longlong(scores[j]); }
    }
  }
  __syncthreads();
  int gc = gcount; if (gc > 256) gc = 256;

  bool sel[TCH];
  int cntSel = 0;
#pragma unroll
  for (int i = 0; i < TCH; ++i) {
    int j = j0 + i;
    bool s = false;
    if (j < DFF) {
      if (key[i] > T) s = true;
      else if (key[i] == T) {
        u64 myk = (u64)__double_as_longlong(scores[j]);
        int r = 0;
        for (int e = 0; e < gc; ++e) {
          u64 ke = gkey[e];
          if (ke > myk || (ke == myk && gidx[e] < j)) r++;
        }
        s = (r < needEq);
      }
    }
    sel[i] = s;
    cntSel += s ? 1 : 0;
  }
  int incl = block_incl_scan(cntSel, tid, wsums);
  int running = incl - cntSel;
#pragma unroll
  for (int i = 0; i < TCH; ++i) {
    int j = j0 + i;
    if (j < DFF) {
      rank[j] = running;
      if (sel[i]) running++;
    }
  }
  if (tid == 0) rank[DFF] = TOPK;
}

// ---------------------------------------------------------------------------
// 3) merged compaction gather: one dispatch covers X (y<128) and W (y>=128).
//    REG-STAGED: all 16 row-loads issued back-to-back into registers (16 KB
//    in flight per wave), THEN convert+scatter to LDS. Removes the 1-load-
//    outstanding latency serialization (was 105 us at ~2.6 TB/s effective).
// ---------------------------------------------------------------------------
__device__ __forceinline__ u16 f2bf_rne(float f) {
  unsigned u = __float_as_uint(f);
  unsigned r = (u + 0x7fffu + ((u >> 16) & 1u)) >> 16;
  return (u16)r;
}

#define GCW 1024
#define GNR 16
#define XBLKS (S_TOK / GNR)   // 128

__global__ __launch_bounds__(256) void compact_gather2_k(const float* __restrict__ x,
                                                         const float* __restrict__ W,
                                                         const int* __restrict__ rank,
                                                         u16* __restrict__ Xg,
                                                         u16* __restrict__ Wg) {
  __shared__ u16 buf[GNR][GCW];   // 32 KiB
  __shared__ int sh_se[2];
  const int by = blockIdx.y;
  const float* src;
  u16* dst;
  int row0;
  if (by < XBLKS) { src = x; dst = Xg; row0 = by * GNR; }
  else            { src = W; dst = Wg; row0 = (by - XBLKS) * GNR; }
  const int c0 = blockIdx.x * GCW;
  if (threadIdx.x == 0) {
    int cend = c0 + GCW; if (cend > DFF) cend = DFF;
    sh_se[0] = rank[c0];
    sh_se[1] = rank[cend];
  }
  // fused pad-zero: (KPAD-TOPK)=77 pad cols x GNR rows by the x==0 blocks
  if (blockIdx.x == 0) {
    for (int idx = threadIdx.x; idx < (KPAD - TOPK) * GNR; idx += 256) {
      int rr = idx / (KPAD - TOPK);
      int k = idx - rr * (KPAD - TOPK);
      dst[(size_t)(row0 + rr) * KPAD + TOPK + k] = 0;
    }
  }

  const int c = c0 + threadIdx.x * 4;
  const bool inb = (c < DFF);

  // hoist rank reads + issue ALL 16 row loads before any dependent use
  int r0 = 0, r1 = 0, r2 = 0, r3 = 0, r4 = 0;
  float4 v[GNR];
  if (inb) {
    r0 = rank[c]; r1 = rank[c + 1]; r2 = rank[c + 2]; r3 = rank[c + 3]; r4 = rank[c + 4];
#pragma unroll
    for (int rr = 0; rr < GNR; ++rr)
      v[rr] = *(const float4*)(src + (size_t)(row0 + rr) * DFF + c);
  }
  __syncthreads();   // pad-zero + sh_se visible; overlaps with loads in flight
  const int start = sh_se[0];
  const int total = sh_se[1] - start;

  if (total > 0 && inb) {
#pragma unroll
    for (int rr = 0; rr < GNR; ++rr) {
      if (r1 > r0) buf[rr][r0 - start] = f2bf_rne(v[rr].x);
      if (r2 > r1) buf[rr][r1 - start] = f2bf_rne(v[rr].y);
      if (r3 > r2) buf[rr][r2 - start] = f2bf_rne(v[rr].z);
      if (r4 > r3) buf[rr][r3 - start] = f2bf_rne(v[rr].w);
    }
  }
  __syncthreads();
  if (total > 0) {
    const int odd = start & 1;
    const int np = (total - odd) >> 1;
#pragma unroll
    for (int rr = 0; rr < GNR; ++rr) {
      u16* d = dst + (size_t)(row0 + rr) * KPAD;
      if (odd && threadIdx.x == 0) d[start] = buf[rr][0];
      const u16* bb = &buf[rr][odd];
      u16* da = d + start + odd;
      for (int t = threadIdx.x; t < np; t += 256) {
        u32 v2 = (u32)bb[2 * t] | ((u32)bb[2 * t + 1] << 16);
        *(u32*)(da + 2 * t) = v2;
      }
      if (((total - odd) & 1) && threadIdx.x == 0) d[start + total - 1] = buf[rr][total - 1];
    }
  }
}

// ---------------------------------------------------------------------------
// 4) NT GEMM, 256x128 tile, BK=64, 8 waves (4M x 2N), single pass over all 70
//    K-tiles. 4-phase counted-vmcnt schedule per tile (T2 swizzle + T3/T4
//    pipeline + T5 setprio). 256 blocks = 1/CU. (unchanged from round 3)
// ---------------------------------------------------------------------------
__device__ __forceinline__ void async_load16(const void* g, void* l) {
  __builtin_amdgcn_global_load_lds(
      (const __attribute__((address_space(1))) void*)g,
      (__attribute__((address_space(3))) void*)l, 16, 0, 0);
}

#define GBAR() do { asm volatile("" ::: "memory"); __builtin_amdgcn_s_barrier(); asm volatile("" ::: "memory"); } while (0)
#define VMCNT2() asm volatile("s_waitcnt vmcnt(2)" ::: "memory")

#define LD_A(D, HF, AF) do {                                                \
  const char* ab_ = (const char*)lds + (D) * 49152 + aBase + (HF) * 4096;   \
  _Pragma("unroll") for (int i_ = 0; i_ < 2; ++i_) {                        \
    AF[i_][0] = *(const short8*)(ab_ + i_ * 2048 + cs0);                    \
    AF[i_][1] = *(const short8*)(ab_ + i_ * 2048 + cs1);                    \
  }                                                                         \
} while (0)

#define LD_B(D, HF, BF) do {                                                \
  const char* bb_ = (const char*)lds + (D) * 49152 + bBase + (HF) * 4096;   \
  _Pragma("unroll") for (int j_ = 0; j_ < 2; ++j_) {                        \
    BF[j_][0] = *(const short8*)(bb_ + j_ * 2048 + cs0);                    \
    BF[j_][1] = *(const short8*)(bb_ + j_ * 2048 + cs1);                    \
  }                                                                         \
} while (0)

#define MQ(HR, HC, AF, BF) do {                                             \
  __builtin_amdgcn_s_setprio(1);                                            \
  _Pragma("unroll") for (int i_ = 0; i_ < 2; ++i_)                          \
    _Pragma("unroll") for (int j_ = 0; j_ < 2; ++j_)                        \
      _Pragma("unroll") for (int k_ = 0; k_ < 2; ++k_)                      \
        acc[(HR) * 2 + i_][(HC) * 2 + j_] = __builtin_amdgcn_mfma_f32_16x16x32_bf16( \
            AF[i_][k_], BF[j_][k_], acc[(HR) * 2 + i_][(HC) * 2 + j_], 0, 0, 0); \
  __builtin_amdgcn_s_setprio(0);                                            \
} while (0)

// stage 128 A-rows (2 loads) of tile tt, half HF, into bufD
#define STAGE_A2(tt, D, HF) do {                                            \
  int ts_ = (tt); if (ts_ > NTILES - 1) ts_ = NTILES - 1;                   \
  const u16* s_ = A + (size_t)(bm + (HF) * 128 + sr0) * KPAD + ts_ * 64 + scc; \
  char* l_ = (char*)lds + (D) * 49152 + (HF) * 16384 + wave * 1024;         \
  async_load16(s_, l_);                                                     \
  async_load16(s_ + (size_t)64 * KPAD, l_ + 8192);                          \
} while (0)

// stage 64 B-rows (1 load) of tile tt, op HF (rows HF*64..), into bufD
#define STAGE_B1(tt, D, HF) do {                                            \
  int ts_ = (tt); if (ts_ > NTILES - 1) ts_ = NTILES - 1;                   \
  const u16* s_ = B + (size_t)(bn + (HF) * 64 + sr0) * KPAD + ts_ * 64 + scc; \
  char* l_ = (char*)lds + (D) * 49152 + 32768 + (HF) * 8192 + wave * 1024;  \
  async_load16(s_, l_);                                                     \
} while (0)

#define ITER(T, D) do {                                                     \
  LD_A(D, 0, afL); LD_B(D, 0, bfL);                                         \
  STAGE_A2((T) + 1, (D) ^ 1, 0);                                            \
  GBAR(); MQ(0, 0, afL, bfL); GBAR();                                       \
  LD_B(D, 1, bfH);                                                          \
  STAGE_A2((T) + 1, (D) ^ 1, 1);                                            \
  GBAR(); MQ(0, 1, afL, bfH); GBAR();                                       \
  LD_A(D, 1, afH);                                                          \
  STAGE_B1((T) + 2, (D), 0);                                                \
  GBAR(); MQ(1, 0, afH, bfL); GBAR();                                       \
  STAGE_B1((T) + 2, (D), 1);                                                \
  MQ(1, 1, afH, bfH); VMCNT2(); GBAR();                                     \
} while (0)

__global__ __launch_bounds__(512, 2) void gemm8_k(const u16* __restrict__ A,
                                                  const u16* __restrict__ B,
                                                  float* __restrict__ C) {
  __shared__ __align__(16) u16 lds[49152];  // 96 KiB
  const int tid = threadIdx.x;
  const int lane = tid & 63;
  const int wave = tid >> 6;
  const int wr = wave >> 1, wc = wave & 1;   // 4M x 2N waves, 64x64 each

  // XCD-aware swizzle: 256 blocks, 32/XCD -> each XCD owns one full bm row
  const int swz = (blockIdx.x & 7) * 32 + (blockIdx.x >> 3);
  const int bm = (swz >> 5) * 256;           // 8 M-tiles
  const int bn = (swz & 31) * 128;           // 32 N-tiles

  // staging lane constants (inverse-swizzled global source)
  const int sr0 = wave * 8 + (lane >> 3);
  const int scc = ((lane & 7) ^ (lane >> 3)) * 8;
  // read-side swizzled column bytes: colpart ^ ((row&7)<<4), row&7 == lane&7
  const int cs0 = ((lane >> 4) * 16) ^ ((lane & 7) << 4);
  const int cs1 = cs0 ^ 64;
  const int aBase = (wr * 64 + (lane & 15)) * 128;
  const int bBase = 32768 + (wc * 64 + (lane & 15)) * 128;

  floatx4 acc[4][4];
#pragma unroll
  for (int i = 0; i < 4; ++i)
#pragma unroll
    for (int j = 0; j < 4; ++j) acc[i][j] = (floatx4){0.f, 0.f, 0.f, 0.f};

  short8 afL[2][2], afH[2][2], bfL[2][2], bfH[2][2];

  // prologue: A(0)->buf0 [4 loads], B(0)->buf0 [2], B(1)->buf1.B [2]
  STAGE_A2(0, 0, 0);
  STAGE_A2(0, 0, 1);
  STAGE_B1(0, 0, 0);
  STAGE_B1(0, 0, 1);
  STAGE_B1(1, 1, 0);
  STAGE_B1(1, 1, 1);
  VMCNT2();   // tile 0 fully landed; B(1) still in flight
  GBAR();

  for (int t2 = 0; t2 < NTILES; t2 += 2) {
    ITER(t2, 0);
    ITER(t2 + 1, 1);
  }

  // C/D layout (verified m89/m91): col = lane&15, row = (lane>>4)*4 + reg
#pragma unroll
  for (int fi = 0; fi < 4; ++fi) {
#pragma unroll
    for (int fj = 0; fj < 4; ++fj) {
      int row = bm + wr * 64 + fi * 16 + (lane >> 4) * 4;
      int col = bn + wc * 64 + fj * 16 + (lane & 15);
      float* p = C + (size_t)row * DMODEL + col;
#pragma unroll
      for (int r = 0; r < 4; ++r) p[(size_t)r * DMODEL] = acc[fi][fj][r];
    }
  }
}

// ---------------------------------------------------------------------------
// launch
// ---------------------------------------------------------------------------
extern "C" void kernel_launch(void* const* d_in, const int* in_sizes, int n_in,
                              void* d_out, int out_size, void* d_ws, size_t ws_size,
                              hipStream_t stream) {
  const float* x = (const float*)d_in[0];  // [2048, 11008]
  const float* W = (const float*)d_in[1];  // [4096, 11008]
  float* out = (float*)d_out;              // [2048, 4096]
  char* ws = (char*)d_ws;

  // workspace layout (~57 MB)
  double* partials = (double*)ws;                        // 1,409,024 B
  double* scores = (double*)(ws + 1409024);              //    88,064 B
  int* rank = (int*)(ws + 1409024 + 88064);              //    44,036 B
  u32* keys = (u32*)(ws + 1409024 + 88064 + 44040);      //    44,032 B
  u16* Xg = (u16*)(ws + (size_t)2097152);                // 2048*4480*2 = 18,350,080
  u16* Wg = (u16*)(ws + (size_t)2097152 + (size_t)S_TOK * KPAD * 2);  // 4096*4480*2

  score_partial_k<<<dim3(43, RSPLIT), 64, 0, stream>>>(x, partials);
  reduce_scores_k<<<43, 256, 0, stream>>>(partials, scores, keys);
  topk32_k<<<1, 1024, 0, stream>>>(keys, scores, rank);
  compact_gather2_k<<<dim3(11, XBLKS + DMODEL / GNR), 256, 0, stream>>>(x, W, rank, Xg, Wg);
  gemm8_k<<<dim3((S_TOK / 256) * (DMODEL / 128)), 512, 0, stream>>>(Xg, Wg, out);
}